// Round 1
// baseline (1929.216 us; speedup 1.0000x reference)
//
#include <hip/hip_runtime.h>

#define NEG_SLOPE 0.2f

__device__ __forceinline__ float lrelu(float x) { return x >= 0.f ? x : NEG_SLOPE * x; }

// ---------------------------------------------------------------- CSR build
__global__ void k_hist(const int* __restrict__ dst, int E, int* __restrict__ counts) {
    int i = blockIdx.x * blockDim.x + threadIdx.x;
    if (i < E) atomicAdd(&counts[dst[i]], 1);
}

// Block-level exclusive scan (512 elems/block), emits block sums.
__global__ void k_scan1(const int* __restrict__ counts, int* __restrict__ excl,
                        int* __restrict__ bsums, int N) {
    __shared__ int sh[512];
    int t = threadIdx.x;
    int i = blockIdx.x * 512 + t;
    int v = (i < N) ? counts[i] : 0;
    sh[t] = v;
    __syncthreads();
    for (int off = 1; off < 512; off <<= 1) {
        int x = (t >= off) ? sh[t - off] : 0;
        __syncthreads();
        sh[t] += x;
        __syncthreads();
    }
    if (i < N) excl[i] = sh[t] - v;         // exclusive within block
    if (t == 511) bsums[blockIdx.x] = sh[511];
}

// Single-block exclusive scan of block sums (nb <= 1024).
__global__ void k_scan2(int* __restrict__ bsums, int nb) {
    __shared__ int sh[1024];
    int t = threadIdx.x;
    int v = (t < nb) ? bsums[t] : 0;
    sh[t] = v;
    __syncthreads();
    for (int off = 1; off < 1024; off <<= 1) {
        int x = (t >= off) ? sh[t - off] : 0;
        __syncthreads();
        sh[t] += x;
        __syncthreads();
    }
    if (t < nb) bsums[t] = sh[t] - v;       // exclusive
}

__global__ void k_scan3(int* __restrict__ rowptr, const int* __restrict__ bsums,
                        int* __restrict__ cursor, int N, int E) {
    int i = blockIdx.x * blockDim.x + threadIdx.x;
    if (i < N) {
        int r = rowptr[i] + bsums[i >> 9];
        rowptr[i] = r;
        cursor[i] = r;
    }
    if (i == 0) rowptr[N] = E;
}

__global__ void k_scatter(const int* __restrict__ src, const int* __restrict__ dst, int E,
                          int* __restrict__ cursor, int* __restrict__ ssrc) {
    int i = blockIdx.x * blockDim.x + threadIdx.x;
    if (i < E) {
        int d = dst[i];
        int pos = atomicAdd(&cursor[d], 1);
        ssrc[pos] = src[i];
    }
}

// ------------------------------------------------------- per-layer kernels
// hs = h @ W ; alpha_src = hs . a_s ; alpha_dst = hs . a_d
// 32 threads per node (D=32), W staged in LDS, h-row broadcast via shfl.
template <int K>
__global__ __launch_bounds__(256) void k_transform(
    const float* __restrict__ h, const float* __restrict__ W,
    const float* __restrict__ a_s, const float* __restrict__ a_d,
    float* __restrict__ hs, float* __restrict__ asrc, float* __restrict__ adst, int N) {
    __shared__ float Ws[K * 32];
    __shared__ float as_s[32], ad_s[32];
    int t = threadIdx.x;
    for (int i = t; i < K * 32; i += blockDim.x) Ws[i] = W[i];
    if (t < 32) { as_s[t] = a_s[t]; ad_s[t] = a_d[t]; }
    __syncthreads();

    int n = blockIdx.x * (blockDim.x >> 5) + (t >> 5);
    int d = t & 31;
    if (n >= N) return;

    float hval = (d < K) ? h[n * K + d] : 0.f;
    float acc = 0.f;
#pragma unroll
    for (int k = 0; k < K; k++) {
        float hk = __shfl(hval, k, 32);
        acc += hk * Ws[k * 32 + d];
    }
    hs[n * 32 + d] = acc;

    float r1 = acc * as_s[d];
    float r2 = acc * ad_s[d];
#pragma unroll
    for (int off = 16; off > 0; off >>= 1) {
        r1 += __shfl_xor(r1, off, 32);
        r2 += __shfl_xor(r2, off, 32);
    }
    if (d == 0) { asrc[n] = r1; adst[n] = r2; }
}

// One wave64 per node. Pass1: 64-lane-parallel max over incoming edges.
// Pass2: 2 edges x 32 dims per iteration; exp-sum + weighted feature sum.
__global__ __launch_bounds__(256) void k_gather(
    const float* __restrict__ hs, const float* __restrict__ asrc,
    const float* __restrict__ adst, const int* __restrict__ rowptr,
    const int* __restrict__ ssrc, const float* __restrict__ bias,
    float* __restrict__ out, int N) {
    int wave = threadIdx.x >> 6;
    int lane = threadIdx.x & 63;
    int n = blockIdx.x * 4 + wave;
    if (n >= N) return;

    int d = lane & 31;
    int eh = lane >> 5;  // which half of the wave
    int start = rowptr[n];
    int end = rowptr[n + 1];

    float adst_n = adst[n];
    float a_self = lrelu(asrc[n] + adst_n);

    // pass 1: segment max (includes self loop)
    float m = a_self;
    for (int e = start + lane; e < end; e += 64) {
        int s = ssrc[e];
        m = fmaxf(m, lrelu(asrc[s] + adst_n));
    }
#pragma unroll
    for (int off = 32; off > 0; off >>= 1) m = fmaxf(m, __shfl_xor(m, off, 64));

    // pass 2: exp-sum + weighted feature accumulation
    float den = 0.f;
    float acc = 0.f;
    if (eh == 0) {
        float exs = __expf(a_self - m);
        den = exs;
        acc = exs * hs[n * 32 + d];
    }
    for (int e = start + eh; e < end; e += 2) {
        int s = ssrc[e];
        float a = lrelu(asrc[s] + adst_n);
        float ex = __expf(a - m);
        den += ex;                      // identical across the 32 lanes of this half
        acc += ex * hs[s * 32 + d];
    }
    // combine the two halves
    acc += __shfl_xor(acc, 32, 64);
    den += __shfl_xor(den, 32, 64);

    if (eh == 0) {
        float o = acc / den + bias[d];
        out[n * 32 + d] = fmaxf(o, 0.f);
    }
}

// ---------------------------------------------------------------- launcher
extern "C" void kernel_launch(void* const* d_in, const int* in_sizes, int n_in,
                              void* d_out, int out_size, void* d_ws, size_t ws_size,
                              hipStream_t stream) {
    const float* x      = (const float*)d_in[0];
    const int*   ei     = (const int*)d_in[1];
    const float* W0     = (const float*)d_in[2];
    const float* a_src0 = (const float*)d_in[3];
    const float* a_dst0 = (const float*)d_in[4];
    const float* b0     = (const float*)d_in[5];
    const float* W      = (const float*)d_in[6];
    const float* a_src  = (const float*)d_in[7];
    const float* a_dst  = (const float*)d_in[8];
    const float* b      = (const float*)d_in[9];

    const int F = 3;
    const int D = 32;
    const int N = in_sizes[0] / F;        // 320000
    const int E = in_sizes[1] / 2;        // 5120000
    const int* src = ei;
    const int* dst = ei + E;

    // workspace carve (all 4-byte types)
    float* HS    = (float*)d_ws;                     // N*32
    float* H1    = HS + (size_t)N * 32;              // N*32
    float* asrcv = H1 + (size_t)N * 32;              // N
    float* adstv = asrcv + N;                        // N
    int* rowptr  = (int*)(adstv + N);                // N+1
    int* cursor  = rowptr + (N + 1);                 // N
    int* counts  = cursor + N;                       // N
    int* bsums   = counts + N;                       // 1024
    int* ssrc    = bsums + 1024;                     // E
    float* outp  = (float*)d_out;

    const int T = 256;

    // ---- CSR build (once; shared by all 3 layers) ----
    hipMemsetAsync(counts, 0, (size_t)N * sizeof(int), stream);
    k_hist<<<(E + T - 1) / T, T, 0, stream>>>(dst, E, counts);
    int nb1 = (N + 511) / 512;  // 625
    k_scan1<<<nb1, 512, 0, stream>>>(counts, rowptr, bsums, N);
    k_scan2<<<1, 1024, 0, stream>>>(bsums, nb1);
    k_scan3<<<(N + T - 1) / T, T, 0, stream>>>(rowptr, bsums, cursor, N, E);
    k_scatter<<<(E + T - 1) / T, T, 0, stream>>>(src, dst, E, cursor, ssrc);

    dim3 gridT(N / 8);   // 8 nodes / block (256 threads, 32/node)
    dim3 gridG(N / 4);   // 4 nodes / block (256 threads, wave64/node)

    // ---- layer 0: x(N,3) -> H1 ----
    k_transform<3><<<gridT, T, 0, stream>>>(x, W0, a_src0, a_dst0, HS, asrcv, adstv, N);
    k_gather<<<gridG, T, 0, stream>>>(HS, asrcv, adstv, rowptr, ssrc, b0, H1, N);

    // ---- layer 1: H1 -> d_out ----
    k_transform<32><<<gridT, T, 0, stream>>>(H1, W, a_src, a_dst, HS, asrcv, adstv, N);
    k_gather<<<gridG, T, 0, stream>>>(HS, asrcv, adstv, rowptr, ssrc, b, outp, N);

    // ---- layer 2: d_out -> d_out ----
    k_transform<32><<<gridT, T, 0, stream>>>(outp, W + 1024, a_src + 32, a_dst + 32,
                                             HS, asrcv, adstv, N);
    k_gather<<<gridG, T, 0, stream>>>(HS, asrcv, adstv, rowptr, ssrc, b + 32, outp, N);
}